// Round 2
// baseline (1447.694 us; speedup 1.0000x reference)
//
#include <hip/hip_runtime.h>
#include <hip/hip_bf16.h>

#define NN 50000
#define NE 400000

typedef unsigned short u16;
typedef __attribute__((ext_vector_type(8))) short short8;
typedef __attribute__((ext_vector_type(4))) float f32x4;
typedef __attribute__((ext_vector_type(4))) unsigned short u16x4;

typedef __attribute__((address_space(1))) const void as1_void;
typedef __attribute__((address_space(3))) void as3_void;

static __device__ __forceinline__ float bf2f(u16 u) {
    return __uint_as_float(((unsigned int)u) << 16);
}
static __device__ __forceinline__ u16 f2bf(float f) {
    unsigned int x = __float_as_uint(f);
    x += 0x7fffu + ((x >> 16) & 1u);
    return (u16)(x >> 16);
}

static __device__ __forceinline__ void gload_lds16(const u16* g, u16* l) {
    __builtin_amdgcn_global_load_lds((as1_void*)g, (as3_void*)l, 16, 0, 0);
}

// ---------------------------------------------------------------------------
// bf16 GEMM: C[M,N] = A[M,K] @ Bt[N,K]^T, epilogue (+bias)(+aux)(relu), bf16 out.
// m97 structure: 128x128 tile, BK=32, 4 waves, 4x4 16x16x32 frags.
// gridDim.y*128 must equal N exactly; M guarded (loads clamped, stores masked).
// ---------------------------------------------------------------------------
__global__ __launch_bounds__(256) void gemm_bt(
    const u16* __restrict__ A, int lda,
    const u16* __restrict__ Bt,
    u16* __restrict__ C, int ldc,
    int M, int K,
    const float* __restrict__ bias,
    const u16* __restrict__ aux, int ld_aux,
    int relu)
{
    __shared__ u16 As[128 * 32];
    __shared__ u16 Bs[128 * 32];

    const int t = threadIdx.x;
    const int w = t >> 6;
    const int lane = t & 63;
    const int quad = lane >> 4;
    const int l15 = lane & 15;
    const int tile_m = blockIdx.x * 128;
    const int tile_n = blockIdx.y * 128;
    const int wm = (w >> 1) * 64;
    const int wn = (w & 1) * 64;

    f32x4 acc[4][4];
#pragma unroll
    for (int r = 0; r < 4; ++r)
#pragma unroll
        for (int c = 0; c < 4; ++c)
            acc[r][c] = (f32x4){0.f, 0.f, 0.f, 0.f};

    int ar0 = tile_m + (t >> 2);      if (ar0 > M - 1) ar0 = M - 1;
    int ar1 = tile_m + 64 + (t >> 2); if (ar1 > M - 1) ar1 = M - 1;
    const int br0 = tile_n + (t >> 2);
    const int br1 = tile_n + 64 + (t >> 2);
    const int koff = (t & 3) * 8;

    u16* lAs0 = As + w * 512;
    u16* lAs1 = As + 2048 + w * 512;
    u16* lBs0 = Bs + w * 512;
    u16* lBs1 = Bs + 2048 + w * 512;

    const u16* Arow0 = A + (size_t)ar0 * lda + koff;
    const u16* Arow1 = A + (size_t)ar1 * lda + koff;
    const u16* Brow0 = Bt + (size_t)br0 * K + koff;
    const u16* Brow1 = Bt + (size_t)br1 * K + koff;

    for (int k0 = 0; k0 < K; k0 += 32) {
        gload_lds16(Arow0 + k0, lAs0);
        gload_lds16(Arow1 + k0, lAs1);
        gload_lds16(Brow0 + k0, lBs0);
        gload_lds16(Brow1 + k0, lBs1);
        __syncthreads();

        short8 af[4], bfr[4];
#pragma unroll
        for (int r = 0; r < 4; ++r)
            af[r] = *(const short8*)&As[(wm + r * 16 + l15) * 32 + quad * 8];
#pragma unroll
        for (int c = 0; c < 4; ++c)
            bfr[c] = *(const short8*)&Bs[(wn + c * 16 + l15) * 32 + quad * 8];
#pragma unroll
        for (int r = 0; r < 4; ++r)
#pragma unroll
            for (int c = 0; c < 4; ++c)
                acc[r][c] = __builtin_amdgcn_mfma_f32_16x16x32_bf16(af[r], bfr[c], acc[r][c], 0, 0, 0);
        __syncthreads();
    }

#pragma unroll
    for (int r = 0; r < 4; ++r) {
#pragma unroll
        for (int c = 0; c < 4; ++c) {
            const int coln = tile_n + wn + c * 16 + l15;
            const float bv = bias ? bias[coln] : 0.0f;
#pragma unroll
            for (int i = 0; i < 4; ++i) {
                const int row = tile_m + wm + r * 16 + quad * 4 + i;
                if (row < M) {
                    float v = acc[r][c][i] + bv;
                    if (aux) v += bf2f(aux[(size_t)row * ld_aux + coln]);
                    if (relu) v = fmaxf(v, 0.f);
                    C[(size_t)row * ldc + coln] = f2bf(v);
                }
            }
        }
    }
}

// ---------------------------------------------------------------------------
// Fused edge message + mean aggregation; Q = eattr@We computed in-register.
// One wave per node; edges CSR-sorted by dst.
// m = relu(Ps[src] + Pd[node] + eattr@We + eb); agg = mean(m).
// P rows are [Ps(256) | Pd(256) | R(256)]. WeC is [32][256] bf16.
// ---------------------------------------------------------------------------
__global__ __launch_bounds__(256) void edge_agg_fused(
    const u16* __restrict__ P,
    const u16* __restrict__ eattr_p,
    const u16* __restrict__ WeC,
    const int* __restrict__ row_start,
    const int* __restrict__ src_perm,
    const float* __restrict__ inv_deg,
    const float* __restrict__ eb,
    u16* __restrict__ agg)
{
    __shared__ u16 Wl[32 * 256];
    // stage We (16 KB) into LDS, vectorized
    for (int i = threadIdx.x; i < 2048; i += 256)
        ((u16x4*)Wl)[i] = ((const u16x4*)WeC)[i];
    __syncthreads();

    const int node = (int)((blockIdx.x * 256 + threadIdx.x) >> 6);
    const int lane = threadIdx.x & 63;
    const int col = lane * 4;

    // hoist this lane's 4 We columns into f32 registers
    f32x4 wf[32];
#pragma unroll
    for (int k = 0; k < 32; ++k) {
        u16x4 wv = *(const u16x4*)&Wl[k * 256 + col];
        wf[k] = (f32x4){bf2f(wv[0]), bf2f(wv[1]), bf2f(wv[2]), bf2f(wv[3])};
    }

    u16x4 pdv = *(const u16x4*)(P + (size_t)node * 768 + 256 + col);
    f32x4 pb;
    pb[0] = bf2f(pdv[0]) + eb[col];
    pb[1] = bf2f(pdv[1]) + eb[col + 1];
    pb[2] = bf2f(pdv[2]) + eb[col + 2];
    pb[3] = bf2f(pdv[3]) + eb[col + 3];

    f32x4 accv = (f32x4){0.f, 0.f, 0.f, 0.f};
    const int s0 = row_start[node], s1 = row_start[node + 1];
    for (int j = s0; j < s1; ++j) {
        const int s = src_perm[j];
        u16x4 ps = *(const u16x4*)(P + (size_t)s * 768 + col);
        const float ev = bf2f(eattr_p[(size_t)j * 32 + (lane & 31)]);
        f32x4 q = pb;
#pragma unroll
        for (int k = 0; k < 32; ++k)
            q += __shfl(ev, k, 64) * wf[k];
        q[0] += bf2f(ps[0]);
        q[1] += bf2f(ps[1]);
        q[2] += bf2f(ps[2]);
        q[3] += bf2f(ps[3]);
        accv[0] += fmaxf(q[0], 0.f);
        accv[1] += fmaxf(q[1], 0.f);
        accv[2] += fmaxf(q[2], 0.f);
        accv[3] += fmaxf(q[3], 0.f);
    }
    const float idg = inv_deg[node];
    u16x4 o;
    o[0] = f2bf(accv[0] * idg);
    o[1] = f2bf(accv[1] * idg);
    o[2] = f2bf(accv[2] * idg);
    o[3] = f2bf(accv[3] * idg);
    *(u16x4*)(agg + (size_t)node * 256 + col) = o;
}

// out[node] = dot(h3[node,:], h2w) + h2b  — one wave per node
__global__ __launch_bounds__(256) void head_out(
    const u16* __restrict__ h3,
    const float* __restrict__ h2w,
    const float* __restrict__ h2b,
    float* __restrict__ out)
{
    const int node = (int)((blockIdx.x * 256 + threadIdx.x) >> 6);
    const int lane = threadIdx.x & 63;
    if (node >= NN) return;
    const int col = lane * 4;
    u16x4 hv = *(const u16x4*)(h3 + (size_t)node * 256 + col);
    float4 wv = *(const float4*)(h2w + col);
    float s = bf2f(hv[0]) * wv.x + bf2f(hv[1]) * wv.y +
              bf2f(hv[2]) * wv.z + bf2f(hv[3]) * wv.w;
    for (int off = 32; off > 0; off >>= 1)
        s += __shfl_down(s, off, 64);
    if (lane == 0) out[node] = s + h2b[0];
}

// ---------------- setup kernels ----------------
__global__ void zero_int(int* p, int n) {
    int i = blockIdx.x * 256 + threadIdx.x;
    if (i < n) p[i] = 0;
}

__global__ void hist_k(const int* __restrict__ ei, int* __restrict__ deg) {
    int e = blockIdx.x * 256 + threadIdx.x;
    if (e < NE) atomicAdd(&deg[ei[NE + e]], 1);
}

__global__ void scan_k(const int* __restrict__ deg, int* __restrict__ row_start,
                       int* __restrict__ cursor, float* __restrict__ inv_deg) {
    __shared__ int sm[1024];
    __shared__ int s_run;
    const int tid = threadIdx.x;
    if (tid == 0) s_run = 0;
    __syncthreads();
    for (int base = 0; base < NN; base += 1024) {
        const int i = base + tid;
        const int v = (i < NN) ? deg[i] : 0;
        sm[tid] = v;
        __syncthreads();
        for (int o = 1; o < 1024; o <<= 1) {
            int tv = (tid >= o) ? sm[tid - o] : 0;
            __syncthreads();
            sm[tid] += tv;
            __syncthreads();
        }
        const int incl = sm[tid];
        const int run = s_run;
        if (i < NN) {
            row_start[i] = run + incl - v;
            cursor[i]    = run + incl - v;
            inv_deg[i]   = 1.0f / fmaxf((float)v, 1.0f);
        }
        __syncthreads();
        if (tid == 1023) s_run = run + incl;
        __syncthreads();
    }
    if (tid == 0) row_start[NN] = s_run;
}

__global__ void scatter_k(const int* __restrict__ ei, const float* __restrict__ eattr,
                          int* __restrict__ cursor, int* __restrict__ src_perm,
                          u16* __restrict__ eattr_p) {
    int e = blockIdx.x * 256 + threadIdx.x;
    if (e >= NE) return;
    int s = ei[e], d = ei[NE + e];
    int pos = atomicAdd(&cursor[d], 1);
    src_perm[pos] = s;
    const float* sr = eattr + (size_t)e * 32;
    u16* dr = eattr_p + (size_t)pos * 32;
#pragma unroll
    for (int j = 0; j < 32; ++j) dr[j] = f2bf(sr[j]);
}

// jobs: tr=1: dst[n*K+k] = bf16(src[k*256+n]); tr=0: dst[i]=bf16(src[i]), count=K*256
struct TJob { const float* src; u16* dst; int K; int ksh; int tr; };
struct TJobs { TJob j[16]; };

__global__ void transpose_k(TJobs jobs) {
    TJob jb = jobs.j[blockIdx.y];
    int idx = blockIdx.x * 256 + threadIdx.x;
    if (idx >= (jb.K << 8)) return;
    if (jb.tr) {
        int n = idx >> jb.ksh;
        int k = idx & (jb.K - 1);
        jb.dst[idx] = f2bf(jb.src[k * 256 + n]);
    } else {
        jb.dst[idx] = f2bf(jb.src[idx]);
    }
}

__global__ void cvt_f32_bf16(const float* __restrict__ src, u16* __restrict__ dst, int n) {
    int i = blockIdx.x * 256 + threadIdx.x;
    if (i < n) dst[i] = f2bf(src[i]);
}

// ---------------------------------------------------------------------------
extern "C" void kernel_launch(void* const* d_in, const int* in_sizes, int n_in,
                              void* d_out, int out_size, void* d_ws, size_t ws_size,
                              hipStream_t stream) {
    const float* x     = (const float*)d_in[0];
    const int*   ei    = (const int*)d_in[1];
    const float* eattr = (const float*)d_in[2];
    const float* e0_w  = (const float*)d_in[3];
    const float* e0_b  = (const float*)d_in[4];
    const float* n0_w  = (const float*)d_in[5];
    const float* n0_b  = (const float*)d_in[6];
    const float* e_w   = (const float*)d_in[7];
    const float* e_b   = (const float*)d_in[8];
    const float* n_w   = (const float*)d_in[9];
    const float* n_b   = (const float*)d_in[10];
    const float* h1_w  = (const float*)d_in[11];
    const float* h1_b  = (const float*)d_in[12];
    const float* h2_w  = (const float*)d_in[13];
    const float* h2_b  = (const float*)d_in[14];
    float* out = (float*)d_out;
    (void)in_sizes; (void)n_in; (void)out_size; (void)ws_size;

    char* base = (char*)d_ws;
    size_t off = 0;
    auto alloc = [&](size_t nbytes) -> void* {
        void* p = base + off;
        off += (nbytes + 255) & ~(size_t)255;
        return p;
    };

    int*   deg       = (int*)alloc(NN * 4);
    int*   row_start = (int*)alloc((NN + 1) * 4);
    int*   cursor    = (int*)alloc(NN * 4);
    float* invdeg    = (float*)alloc(NN * 4);
    int*   src_perm  = (int*)alloc(NE * 4);
    u16*   eattr_p   = (u16*)alloc((size_t)NE * 32 * 2);
    u16*   WcatT0    = (u16*)alloc(768 * 128 * 2);
    u16*   WcatT1    = (u16*)alloc(768 * 256 * 2);
    u16*   WcatT2    = (u16*)alloc(768 * 256 * 2);
    u16*   WeC0      = (u16*)alloc(32 * 256 * 2);
    u16*   WeC1      = (u16*)alloc(32 * 256 * 2);
    u16*   WeC2      = (u16*)alloc(32 * 256 * 2);
    u16*   NbT0      = (u16*)alloc(256 * 256 * 2);
    u16*   NbT1      = (u16*)alloc(256 * 256 * 2);
    u16*   NbT2      = (u16*)alloc(256 * 256 * 2);
    u16*   H1T       = (u16*)alloc(256 * 256 * 2);
    u16*   P         = (u16*)alloc((size_t)NN * 768 * 2);
    u16*   aggb      = (u16*)alloc((size_t)NN * 256 * 2);
    u16*   hb        = (u16*)alloc((size_t)NN * 256 * 2);
    u16*   xb        = aggb;  // alias: xb dead before aggb first written

    // ---- CSR build + weight prep ----
    zero_int<<<(NN + 255) / 256, 256, 0, stream>>>(deg, NN);
    hist_k<<<(NE + 255) / 256, 256, 0, stream>>>(ei, deg);
    scan_k<<<1, 1024, 0, stream>>>(deg, row_start, cursor, invdeg);
    scatter_k<<<(NE + 255) / 256, 256, 0, stream>>>(ei, eattr, cursor, src_perm, eattr_p);

    const float* ew2 = e_w + 544 * 256;
    const float* nw2 = n_w + 512 * 256;

    TJobs tj;
    auto setj = [&](int i, const float* s, u16* d, int K, int tr) {
        tj.j[i].src = s; tj.j[i].dst = d; tj.j[i].K = K; tj.j[i].tr = tr;
        tj.j[i].ksh = (K == 256) ? 8 : (K == 128 ? 7 : 5);
    };
    setj(0,  e0_w,             WcatT0,             128, 1);
    setj(1,  e0_w + 128 * 256, WcatT0 + 256 * 128, 128, 1);
    setj(2,  n0_w,             WcatT0 + 512 * 128, 128, 1);
    setj(3,  n0_w + 128 * 256, NbT0,               256, 1);
    setj(4,  e_w,              WcatT1,             256, 1);
    setj(5,  e_w + 256 * 256,  WcatT1 + 256 * 256, 256, 1);
    setj(6,  n_w,              WcatT1 + 512 * 256, 256, 1);
    setj(7,  n_w + 256 * 256,  NbT1,               256, 1);
    setj(8,  ew2,              WcatT2,             256, 1);
    setj(9,  ew2 + 256 * 256,  WcatT2 + 256 * 256, 256, 1);
    setj(10, nw2,              WcatT2 + 512 * 256, 256, 1);
    setj(11, nw2 + 256 * 256,  NbT2,               256, 1);
    setj(12, h1_w,             H1T,                256, 1);
    setj(13, e0_w + 256 * 256, WeC0,               32,  0);
    setj(14, e_w + 512 * 256,  WeC1,               32,  0);
    setj(15, ew2 + 512 * 256,  WeC2,               32,  0);
    transpose_k<<<dim3(256, 16), 256, 0, stream>>>(tj);

    cvt_f32_bf16<<<(NN * 128 + 255) / 256, 256, 0, stream>>>(x, xb, NN * 128);

    const int MT = (NN + 127) / 128;  // 391
    u16* WcatT[3] = {WcatT0, WcatT1, WcatT2};
    u16* WeC[3]   = {WeC0, WeC1, WeC2};
    u16* NbT[3]   = {NbT0, NbT1, NbT2};
    const float* ebs[3] = {e0_b, e_b, e_b + 256};
    const float* nbs[3] = {n0_b, n_b, n_b + 256};

    for (int l = 0; l < 3; ++l) {
        const u16* hin = (l == 0) ? xb : hb;
        const int kin = (l == 0) ? 128 : 256;
        // P = hin @ [Ws | Wd | ntop]   -> [NN, 768]
        gemm_bt<<<dim3(MT, 6), 256, 0, stream>>>(hin, kin, WcatT[l], P, 768, NN, kin,
                                                 nullptr, nullptr, 0, 0);
        // agg = mean_dst relu(Ps[src] + Pd[dst] + eattr@We + eb)
        edge_agg_fused<<<NN / 4, 256, 0, stream>>>(P, eattr_p, WeC[l], row_start,
                                                   src_perm, invdeg, ebs[l], aggb);
        // h = relu(agg @ nbot + R + nb)
        gemm_bt<<<dim3(MT, 2), 256, 0, stream>>>(aggb, 256, NbT[l], hb, 256, NN, 256,
                                                 nbs[l], P + 512, 768, 1);
    }
    // head: h3 = relu(h @ h1_w + h1_b); out = h3 @ h2_w + h2_b
    gemm_bt<<<dim3(MT, 2), 256, 0, stream>>>(hb, 256, H1T, aggb, 256, NN, 256,
                                             h1_b, nullptr, 0, 1);
    head_out<<<NN / 4, 256, 0, stream>>>(aggb, h2_w, h2_b, out);
}

// Round 3
// 1075.610 us; speedup vs baseline: 1.3459x; 1.3459x over previous
//
#include <hip/hip_runtime.h>
#include <hip/hip_bf16.h>
#include <hip/hip_fp16.h>

#define NN 50000
#define NE 400000

typedef unsigned short u16;
typedef unsigned int u32;
typedef __attribute__((ext_vector_type(8))) short short8;
typedef __attribute__((ext_vector_type(4))) float f32x4;
typedef __attribute__((ext_vector_type(4))) unsigned short u16x4;
typedef __attribute__((ext_vector_type(2))) _Float16 h2;

typedef __attribute__((address_space(1))) const void as1_void;
typedef __attribute__((address_space(3))) void as3_void;

static __device__ __forceinline__ float bf2f(u16 u) {
    return __uint_as_float(((u32)u) << 16);
}
static __device__ __forceinline__ u16 f2bf(float f) {
    u32 x = __float_as_uint(f);
    x += 0x7fffu + ((x >> 16) & 1u);
    return (u16)(x >> 16);
}
static __device__ __forceinline__ u32 packh2(float a, float b) {
    return ((u32)__half_as_ushort(__float2half(b)) << 16) |
           (u32)__half_as_ushort(__float2half(a));
}
static __device__ __forceinline__ float fdot2u(u32 a, u32 b, float c) {
    return __builtin_amdgcn_fdot2(__builtin_bit_cast(h2, a),
                                  __builtin_bit_cast(h2, b), c, false);
}

static __device__ __forceinline__ void gload_lds16(const u16* g, u16* l) {
    __builtin_amdgcn_global_load_lds((as1_void*)g, (as3_void*)l, 16, 0, 0);
}

// ---------------------------------------------------------------------------
// bf16 GEMM: C[M,N] = A[M,K] @ Bt[N,K]^T, epilogue (+bias)(+aux)(relu), bf16 out.
// m97 structure: 128x128 tile, BK=32, 4 waves, 4x4 16x16x32 frags.
// gridDim.y*128 must equal N exactly; M guarded (loads clamped, stores masked).
// ---------------------------------------------------------------------------
__global__ __launch_bounds__(256) void gemm_bt(
    const u16* __restrict__ A, int lda,
    const u16* __restrict__ Bt,
    u16* __restrict__ C, int ldc,
    int M, int K,
    const float* __restrict__ bias,
    const u16* __restrict__ aux, int ld_aux,
    int relu)
{
    __shared__ u16 As[128 * 32];
    __shared__ u16 Bs[128 * 32];

    const int t = threadIdx.x;
    const int w = t >> 6;
    const int lane = t & 63;
    const int quad = lane >> 4;
    const int l15 = lane & 15;
    const int tile_m = blockIdx.x * 128;
    const int tile_n = blockIdx.y * 128;
    const int wm = (w >> 1) * 64;
    const int wn = (w & 1) * 64;

    f32x4 acc[4][4];
#pragma unroll
    for (int r = 0; r < 4; ++r)
#pragma unroll
        for (int c = 0; c < 4; ++c)
            acc[r][c] = (f32x4){0.f, 0.f, 0.f, 0.f};

    int ar0 = tile_m + (t >> 2);      if (ar0 > M - 1) ar0 = M - 1;
    int ar1 = tile_m + 64 + (t >> 2); if (ar1 > M - 1) ar1 = M - 1;
    const int br0 = tile_n + (t >> 2);
    const int br1 = tile_n + 64 + (t >> 2);
    const int koff = (t & 3) * 8;

    u16* lAs0 = As + w * 512;
    u16* lAs1 = As + 2048 + w * 512;
    u16* lBs0 = Bs + w * 512;
    u16* lBs1 = Bs + 2048 + w * 512;

    const u16* Arow0 = A + (size_t)ar0 * lda + koff;
    const u16* Arow1 = A + (size_t)ar1 * lda + koff;
    const u16* Brow0 = Bt + (size_t)br0 * K + koff;
    const u16* Brow1 = Bt + (size_t)br1 * K + koff;

    for (int k0 = 0; k0 < K; k0 += 32) {
        gload_lds16(Arow0 + k0, lAs0);
        gload_lds16(Arow1 + k0, lAs1);
        gload_lds16(Brow0 + k0, lBs0);
        gload_lds16(Brow1 + k0, lBs1);
        __syncthreads();

        short8 af[4], bfr[4];
#pragma unroll
        for (int r = 0; r < 4; ++r)
            af[r] = *(const short8*)&As[(wm + r * 16 + l15) * 32 + quad * 8];
#pragma unroll
        for (int c = 0; c < 4; ++c)
            bfr[c] = *(const short8*)&Bs[(wn + c * 16 + l15) * 32 + quad * 8];
#pragma unroll
        for (int r = 0; r < 4; ++r)
#pragma unroll
            for (int c = 0; c < 4; ++c)
                acc[r][c] = __builtin_amdgcn_mfma_f32_16x16x32_bf16(af[r], bfr[c], acc[r][c], 0, 0, 0);
        __syncthreads();
    }

#pragma unroll
    for (int r = 0; r < 4; ++r) {
#pragma unroll
        for (int c = 0; c < 4; ++c) {
            const int coln = tile_n + wn + c * 16 + l15;
            const float bv = bias ? bias[coln] : 0.0f;
#pragma unroll
            for (int i = 0; i < 4; ++i) {
                const int row = tile_m + wm + r * 16 + quad * 4 + i;
                if (row < M) {
                    float v = acc[r][c][i] + bv;
                    if (aux) v += bf2f(aux[(size_t)row * ld_aux + coln]);
                    if (relu) v = fmaxf(v, 0.f);
                    C[(size_t)row * ldc + coln] = f2bf(v);
                }
            }
        }
    }
}

// ---------------------------------------------------------------------------
// Fused edge message + mean aggregation; Q = eattr@We via readlane + v_dot2.
// One wave per node; edges CSR-sorted by dst.
// m = relu(Ps[src] + Pd[node] + eattr@We + eb); agg = mean(m).
// P rows are [Ps(256) | Pd(256) | R(256)].
// WePk: [16 kpairs][256 cols] u32, each = packed f16 {We[2kp][c], We[2kp+1][c]}.
// eattr_p32: [NE][16] u32 packed f16 pairs, CSR-permuted.
// ---------------------------------------------------------------------------
__global__ __launch_bounds__(256) void edge_agg_fused(
    const u16* __restrict__ P,
    const u32* __restrict__ eattr_p32,
    const u32* __restrict__ WePk,
    const int* __restrict__ row_start,
    const int* __restrict__ src_perm,
    const float* __restrict__ inv_deg,
    const float* __restrict__ eb,
    u16* __restrict__ agg)
{
    const int node = (int)((blockIdx.x * 256 + threadIdx.x) >> 6);
    const int lane = threadIdx.x & 63;
    const int l15 = lane & 15;
    const int col = lane * 4;

    // this lane's 4 columns of We, packed f16 pairs: 16 kpairs x uint4
    uint4 wpk[16];
#pragma unroll
    for (int kp = 0; kp < 16; ++kp)
        wpk[kp] = *(const uint4*)(WePk + kp * 256 + col);

    u16x4 pdv = *(const u16x4*)(P + (size_t)node * 768 + 256 + col);
    f32x4 pb;
    pb[0] = bf2f(pdv[0]) + eb[col];
    pb[1] = bf2f(pdv[1]) + eb[col + 1];
    pb[2] = bf2f(pdv[2]) + eb[col + 2];
    pb[3] = bf2f(pdv[3]) + eb[col + 3];

    f32x4 accv = (f32x4){0.f, 0.f, 0.f, 0.f};
    const int s0r = row_start[node], s1r = row_start[node + 1];

    if (s1r > s0r) {
        const int jlast = s1r - 1;
        // depth-2 pipeline prolog
        int j1 = (s0r + 1 < jlast) ? s0r + 1 : jlast;
        int sa = src_perm[s0r];
        int sb = src_perm[j1];
        u16x4 psa = *(const u16x4*)(P + (size_t)sa * 768 + col);
        u16x4 psb = *(const u16x4*)(P + (size_t)sb * 768 + col);
        u32 eva = eattr_p32[(size_t)s0r * 16 + l15];
        u32 evb = eattr_p32[(size_t)j1 * 16 + l15];

        for (int j = s0r; j < s1r; ++j) {
            // issue prefetch for j+2
            int jc = (j + 2 < jlast) ? j + 2 : jlast;
            int sn = src_perm[jc];
            u16x4 psn = *(const u16x4*)(P + (size_t)sn * 768 + col);
            u32 evn = eattr_p32[(size_t)jc * 16 + l15];

            // compute with current (eva, psa)
            f32x4 q = pb;
#pragma unroll
            for (int kp = 0; kp < 16; ++kp) {
                u32 evk = (u32)__builtin_amdgcn_readlane((int)eva, kp);
                q[0] = fdot2u(evk, wpk[kp].x, q[0]);
                q[1] = fdot2u(evk, wpk[kp].y, q[1]);
                q[2] = fdot2u(evk, wpk[kp].z, q[2]);
                q[3] = fdot2u(evk, wpk[kp].w, q[3]);
            }
            q[0] += bf2f(psa[0]);
            q[1] += bf2f(psa[1]);
            q[2] += bf2f(psa[2]);
            q[3] += bf2f(psa[3]);
            accv[0] += fmaxf(q[0], 0.f);
            accv[1] += fmaxf(q[1], 0.f);
            accv[2] += fmaxf(q[2], 0.f);
            accv[3] += fmaxf(q[3], 0.f);

            psa = psb; eva = evb;
            psb = psn; evb = evn;
        }
    }

    const float idg = inv_deg[node];
    u16x4 o;
    o[0] = f2bf(accv[0] * idg);
    o[1] = f2bf(accv[1] * idg);
    o[2] = f2bf(accv[2] * idg);
    o[3] = f2bf(accv[3] * idg);
    *(u16x4*)(agg + (size_t)node * 256 + col) = o;
}

// out[node] = dot(h3[node,:], h2w) + h2b  — one wave per node
__global__ __launch_bounds__(256) void head_out(
    const u16* __restrict__ h3,
    const float* __restrict__ h2w,
    const float* __restrict__ h2b,
    float* __restrict__ out)
{
    const int node = (int)((blockIdx.x * 256 + threadIdx.x) >> 6);
    const int lane = threadIdx.x & 63;
    if (node >= NN) return;
    const int col = lane * 4;
    u16x4 hv = *(const u16x4*)(h3 + (size_t)node * 256 + col);
    float4 wv = *(const float4*)(h2w + col);
    float s = bf2f(hv[0]) * wv.x + bf2f(hv[1]) * wv.y +
              bf2f(hv[2]) * wv.z + bf2f(hv[3]) * wv.w;
    for (int off = 32; off > 0; off >>= 1)
        s += __shfl_down(s, off, 64);
    if (lane == 0) out[node] = s + h2b[0];
}

// ---------------- setup kernels ----------------
__global__ void zero_int(int* p, int n) {
    int i = blockIdx.x * 256 + threadIdx.x;
    if (i < n) p[i] = 0;
}

__global__ void hist_k(const int* __restrict__ ei, int* __restrict__ deg) {
    int e = blockIdx.x * 256 + threadIdx.x;
    if (e < NE) atomicAdd(&deg[ei[NE + e]], 1);
}

// single block, 1024 threads: chunk-sum + one log-scan + per-chunk writeback
__global__ void scan_k(const int* __restrict__ deg, int* __restrict__ row_start,
                       int* __restrict__ cursor, float* __restrict__ inv_deg) {
    __shared__ int sm[1024];
    const int tid = threadIdx.x;
    const int CH = (NN + 1023) / 1024;  // 49
    const int base = tid * CH;
    int sum = 0;
#pragma unroll 1
    for (int i = 0; i < CH; ++i) {
        int idx = base + i;
        if (idx < NN) sum += deg[idx];
    }
    sm[tid] = sum;
    __syncthreads();
    for (int o = 1; o < 1024; o <<= 1) {
        int tv = (tid >= o) ? sm[tid - o] : 0;
        __syncthreads();
        sm[tid] += tv;
        __syncthreads();
    }
    int run = sm[tid] - sum;  // exclusive prefix of this chunk
#pragma unroll 1
    for (int i = 0; i < CH; ++i) {
        int idx = base + i;
        if (idx < NN) {
            int v = deg[idx];
            row_start[idx] = run;
            cursor[idx]    = run;
            inv_deg[idx]   = 1.0f / fmaxf((float)v, 1.0f);
            run += v;
        }
    }
    if (tid == 1023) row_start[NN] = sm[1023];
}

__global__ void scatter_k(const int* __restrict__ ei, const float* __restrict__ eattr,
                          int* __restrict__ cursor, int* __restrict__ src_perm,
                          u32* __restrict__ eattr_p32) {
    int e = blockIdx.x * 256 + threadIdx.x;
    if (e >= NE) return;
    int s = ei[e], d = ei[NE + e];
    int pos = atomicAdd(&cursor[d], 1);
    src_perm[pos] = s;
    const float* sr = eattr + (size_t)e * 32;
    u32* dr = eattr_p32 + (size_t)pos * 16;
#pragma unroll
    for (int j = 0; j < 16; ++j)
        dr[j] = packh2(sr[2 * j], sr[2 * j + 1]);
}

// jobs: tr=1: dst[n*K+k] = bf16(src[k*256+n])
//       tr=2: We pack: dst32[kp*256+c] = packh2(src[2kp*256+c], src[(2kp+1)*256+c]), count=K<<8 with K=16
struct TJob { const float* src; u16* dst; int K; int ksh; int tr; };
struct TJobs { TJob j[16]; };

__global__ void transpose_k(TJobs jobs) {
    TJob jb = jobs.j[blockIdx.y];
    int idx = blockIdx.x * 256 + threadIdx.x;
    if (idx >= (jb.K << 8)) return;
    if (jb.tr == 1) {
        int n = idx >> jb.ksh;
        int k = idx & (jb.K - 1);
        jb.dst[idx] = f2bf(jb.src[k * 256 + n]);
    } else {
        int kp = idx >> 8;
        int c = idx & 255;
        ((u32*)jb.dst)[idx] = packh2(jb.src[(2 * kp) * 256 + c],
                                     jb.src[(2 * kp + 1) * 256 + c]);
    }
}

__global__ void cvt_f32_bf16(const float* __restrict__ src, u16* __restrict__ dst, int n) {
    int i = blockIdx.x * 256 + threadIdx.x;
    if (i < n) dst[i] = f2bf(src[i]);
}

// ---------------------------------------------------------------------------
extern "C" void kernel_launch(void* const* d_in, const int* in_sizes, int n_in,
                              void* d_out, int out_size, void* d_ws, size_t ws_size,
                              hipStream_t stream) {
    const float* x     = (const float*)d_in[0];
    const int*   ei    = (const int*)d_in[1];
    const float* eattr = (const float*)d_in[2];
    const float* e0_w  = (const float*)d_in[3];
    const float* e0_b  = (const float*)d_in[4];
    const float* n0_w  = (const float*)d_in[5];
    const float* n0_b  = (const float*)d_in[6];
    const float* e_w   = (const float*)d_in[7];
    const float* e_b   = (const float*)d_in[8];
    const float* n_w   = (const float*)d_in[9];
    const float* n_b   = (const float*)d_in[10];
    const float* h1_w  = (const float*)d_in[11];
    const float* h1_b  = (const float*)d_in[12];
    const float* h2_w  = (const float*)d_in[13];
    const float* h2_b  = (const float*)d_in[14];
    float* out = (float*)d_out;
    (void)in_sizes; (void)n_in; (void)out_size; (void)ws_size;

    char* base = (char*)d_ws;
    size_t off = 0;
    auto alloc = [&](size_t nbytes) -> void* {
        void* p = base + off;
        off += (nbytes + 255) & ~(size_t)255;
        return p;
    };

    int*   deg       = (int*)alloc(NN * 4);
    int*   row_start = (int*)alloc((NN + 1) * 4);
    int*   cursor    = (int*)alloc(NN * 4);
    float* invdeg    = (float*)alloc(NN * 4);
    int*   src_perm  = (int*)alloc(NE * 4);
    u32*   eattr_p32 = (u32*)alloc((size_t)NE * 16 * 4);
    u16*   WcatT0    = (u16*)alloc(768 * 128 * 2);
    u16*   WcatT1    = (u16*)alloc(768 * 256 * 2);
    u16*   WcatT2    = (u16*)alloc(768 * 256 * 2);
    u32*   WePk0     = (u32*)alloc(16 * 256 * 4);
    u32*   WePk1     = (u32*)alloc(16 * 256 * 4);
    u32*   WePk2     = (u32*)alloc(16 * 256 * 4);
    u16*   NbT0      = (u16*)alloc(256 * 256 * 2);
    u16*   NbT1      = (u16*)alloc(256 * 256 * 2);
    u16*   NbT2      = (u16*)alloc(256 * 256 * 2);
    u16*   H1T       = (u16*)alloc(256 * 256 * 2);
    u16*   P         = (u16*)alloc((size_t)NN * 768 * 2);
    u16*   aggb      = (u16*)alloc((size_t)NN * 256 * 2);
    u16*   hb        = (u16*)alloc((size_t)NN * 256 * 2);
    u16*   xb        = aggb;  // alias: xb dead before aggb first written

    // ---- CSR build + weight prep ----
    zero_int<<<(NN + 255) / 256, 256, 0, stream>>>(deg, NN);
    hist_k<<<(NE + 255) / 256, 256, 0, stream>>>(ei, deg);
    scan_k<<<1, 1024, 0, stream>>>(deg, row_start, cursor, invdeg);
    scatter_k<<<(NE + 255) / 256, 256, 0, stream>>>(ei, eattr, cursor, src_perm, eattr_p32);

    const float* ew2 = e_w + 544 * 256;
    const float* nw2 = n_w + 512 * 256;

    TJobs tj;
    auto setj = [&](int i, const float* s, void* d, int K, int tr) {
        tj.j[i].src = s; tj.j[i].dst = (u16*)d; tj.j[i].K = K; tj.j[i].tr = tr;
        tj.j[i].ksh = (K == 256) ? 8 : (K == 128 ? 7 : 5);
    };
    setj(0,  e0_w,             WcatT0,             128, 1);
    setj(1,  e0_w + 128 * 256, WcatT0 + 256 * 128, 128, 1);
    setj(2,  n0_w,             WcatT0 + 512 * 128, 128, 1);
    setj(3,  n0_w + 128 * 256, NbT0,               256, 1);
    setj(4,  e_w,              WcatT1,             256, 1);
    setj(5,  e_w + 256 * 256,  WcatT1 + 256 * 256, 256, 1);
    setj(6,  n_w,              WcatT1 + 512 * 256, 256, 1);
    setj(7,  n_w + 256 * 256,  NbT1,               256, 1);
    setj(8,  ew2,              WcatT2,             256, 1);
    setj(9,  ew2 + 256 * 256,  WcatT2 + 256 * 256, 256, 1);
    setj(10, nw2,              WcatT2 + 512 * 256, 256, 1);
    setj(11, nw2 + 256 * 256,  NbT2,               256, 1);
    setj(12, h1_w,             H1T,                256, 1);
    setj(13, e0_w + 256 * 256, WePk0,              16,  2);
    setj(14, e_w + 512 * 256,  WePk1,              16,  2);
    setj(15, ew2 + 512 * 256,  WePk2,              16,  2);
    transpose_k<<<dim3(256, 16), 256, 0, stream>>>(tj);

    cvt_f32_bf16<<<(NN * 128 + 255) / 256, 256, 0, stream>>>(x, xb, NN * 128);

    const int MT = (NN + 127) / 128;  // 391
    u16* WcatT[3] = {WcatT0, WcatT1, WcatT2};
    u32* WePk[3]  = {WePk0, WePk1, WePk2};
    u16* NbT[3]   = {NbT0, NbT1, NbT2};
    const float* ebs[3] = {e0_b, e_b, e_b + 256};
    const float* nbs[3] = {n0_b, n_b, n_b + 256};

    for (int l = 0; l < 3; ++l) {
        const u16* hin = (l == 0) ? xb : hb;
        const int kin = (l == 0) ? 128 : 256;
        // P = hin @ [Ws | Wd | ntop]   -> [NN, 768]
        gemm_bt<<<dim3(MT, 6), 256, 0, stream>>>(hin, kin, WcatT[l], P, 768, NN, kin,
                                                 nullptr, nullptr, 0, 0);
        // agg = mean_dst relu(Ps[src] + Pd[dst] + eattr@We + eb)
        edge_agg_fused<<<NN / 4, 256, 0, stream>>>(P, eattr_p32, WePk[l], row_start,
                                                   src_perm, invdeg, ebs[l], aggb);
        // h = relu(agg @ nbot + R + nb)
        gemm_bt<<<dim3(MT, 2), 256, 0, stream>>>(aggb, 256, NbT[l], hb, 256, NN, 256,
                                                 nbs[l], P + 512, 768, 1);
    }
    // head: h3 = relu(h @ h1_w + h1_b); out = h3 @ h2_w + h2_b
    gemm_bt<<<dim3(MT, 2), 256, 0, stream>>>(hb, 256, H1T, aggb, 256, NN, 256,
                                             h1_b, nullptr, 0, 1);
    head_out<<<NN / 4, 256, 0, stream>>>(aggb, h2_w, h2_b, out);
}

// Round 4
// 938.947 us; speedup vs baseline: 1.5418x; 1.1455x over previous
//
#include <hip/hip_runtime.h>
#include <hip/hip_bf16.h>
#include <hip/hip_fp16.h>

#define NN 50000
#define NE 400000
#define NBLK 196  // ceil(NN/256)

typedef unsigned short u16;
typedef unsigned int u32;
typedef __attribute__((ext_vector_type(8))) short short8;
typedef __attribute__((ext_vector_type(4))) float f32x4;
typedef __attribute__((ext_vector_type(4))) unsigned short u16x4;
typedef __attribute__((ext_vector_type(2))) _Float16 h2;

typedef __attribute__((address_space(1))) const void as1_void;
typedef __attribute__((address_space(3))) void as3_void;

static __device__ __forceinline__ float bf2f(u16 u) {
    return __uint_as_float(((u32)u) << 16);
}
static __device__ __forceinline__ u16 f2bf(float f) {
    u32 x = __float_as_uint(f);
    x += 0x7fffu + ((x >> 16) & 1u);
    return (u16)(x >> 16);
}
static __device__ __forceinline__ u32 packh2(float a, float b) {
    return ((u32)__half_as_ushort(__float2half(b)) << 16) |
           (u32)__half_as_ushort(__float2half(a));
}
static __device__ __forceinline__ float fdot2u(u32 a, u32 b, float c) {
    return __builtin_amdgcn_fdot2(__builtin_bit_cast(h2, a),
                                  __builtin_bit_cast(h2, b), c, false);
}

static __device__ __forceinline__ void gload_lds16(const u16* g, u16* l) {
    __builtin_amdgcn_global_load_lds((as1_void*)g, (as3_void*)l, 16, 0, 0);
}

// ---------------------------------------------------------------------------
// bf16 GEMM: C[M,N] = A[M,K] @ Bt[N,K]^T, epilogue (+bias)(+aux)(relu), bf16 out.
// m97 structure: 128x128 tile, BK=32, 4 waves, 4x4 16x16x32 frags.
// gridDim.y*128 must equal N exactly; M guarded (loads clamped, stores masked).
// ---------------------------------------------------------------------------
__global__ __launch_bounds__(256) void gemm_bt(
    const u16* __restrict__ A, int lda,
    const u16* __restrict__ Bt,
    u16* __restrict__ C, int ldc,
    int M, int K,
    const float* __restrict__ bias,
    const u16* __restrict__ aux, int ld_aux,
    int relu)
{
    __shared__ u16 As[128 * 32];
    __shared__ u16 Bs[128 * 32];

    const int t = threadIdx.x;
    const int w = t >> 6;
    const int lane = t & 63;
    const int quad = lane >> 4;
    const int l15 = lane & 15;
    const int tile_m = blockIdx.x * 128;
    const int tile_n = blockIdx.y * 128;
    const int wm = (w >> 1) * 64;
    const int wn = (w & 1) * 64;

    f32x4 acc[4][4];
#pragma unroll
    for (int r = 0; r < 4; ++r)
#pragma unroll
        for (int c = 0; c < 4; ++c)
            acc[r][c] = (f32x4){0.f, 0.f, 0.f, 0.f};

    int ar0 = tile_m + (t >> 2);      if (ar0 > M - 1) ar0 = M - 1;
    int ar1 = tile_m + 64 + (t >> 2); if (ar1 > M - 1) ar1 = M - 1;
    const int br0 = tile_n + (t >> 2);
    const int br1 = tile_n + 64 + (t >> 2);
    const int koff = (t & 3) * 8;

    u16* lAs0 = As + w * 512;
    u16* lAs1 = As + 2048 + w * 512;
    u16* lBs0 = Bs + w * 512;
    u16* lBs1 = Bs + 2048 + w * 512;

    const u16* Arow0 = A + (size_t)ar0 * lda + koff;
    const u16* Arow1 = A + (size_t)ar1 * lda + koff;
    const u16* Brow0 = Bt + (size_t)br0 * K + koff;
    const u16* Brow1 = Bt + (size_t)br1 * K + koff;

    for (int k0 = 0; k0 < K; k0 += 32) {
        gload_lds16(Arow0 + k0, lAs0);
        gload_lds16(Arow1 + k0, lAs1);
        gload_lds16(Brow0 + k0, lBs0);
        gload_lds16(Brow1 + k0, lBs1);
        __syncthreads();

        short8 af[4], bfr[4];
#pragma unroll
        for (int r = 0; r < 4; ++r)
            af[r] = *(const short8*)&As[(wm + r * 16 + l15) * 32 + quad * 8];
#pragma unroll
        for (int c = 0; c < 4; ++c)
            bfr[c] = *(const short8*)&Bs[(wn + c * 16 + l15) * 32 + quad * 8];
#pragma unroll
        for (int r = 0; r < 4; ++r)
#pragma unroll
            for (int c = 0; c < 4; ++c)
                acc[r][c] = __builtin_amdgcn_mfma_f32_16x16x32_bf16(af[r], bfr[c], acc[r][c], 0, 0, 0);
        __syncthreads();
    }

#pragma unroll
    for (int r = 0; r < 4; ++r) {
#pragma unroll
        for (int c = 0; c < 4; ++c) {
            const int coln = tile_n + wn + c * 16 + l15;
            const float bv = bias ? bias[coln] : 0.0f;
#pragma unroll
            for (int i = 0; i < 4; ++i) {
                const int row = tile_m + wm + r * 16 + quad * 4 + i;
                if (row < M) {
                    float v = acc[r][c][i] + bv;
                    if (aux) v += bf2f(aux[(size_t)row * ld_aux + coln]);
                    if (relu) v = fmaxf(v, 0.f);
                    C[(size_t)row * ldc + coln] = f2bf(v);
                }
            }
        }
    }
}

// ---------------------------------------------------------------------------
// Fused edge message + mean aggregation; Q = eattr@We via readlane + v_dot2.
// One wave per node; edges CSR-sorted by dst.
// ---------------------------------------------------------------------------
__global__ __launch_bounds__(256) void edge_agg_fused(
    const u16* __restrict__ P,
    const u32* __restrict__ eattr_p32,
    const u32* __restrict__ WePk,
    const int* __restrict__ row_start,
    const int* __restrict__ src_perm,
    const float* __restrict__ inv_deg,
    const float* __restrict__ eb,
    u16* __restrict__ agg)
{
    const int node = (int)((blockIdx.x * 256 + threadIdx.x) >> 6);
    const int lane = threadIdx.x & 63;
    const int l15 = lane & 15;
    const int col = lane * 4;

    // this lane's 4 columns of We, packed f16 pairs: 16 kpairs x uint4
    uint4 wpk[16];
#pragma unroll
    for (int kp = 0; kp < 16; ++kp)
        wpk[kp] = *(const uint4*)(WePk + kp * 256 + col);

    u16x4 pdv = *(const u16x4*)(P + (size_t)node * 768 + 256 + col);
    f32x4 pb;
    pb[0] = bf2f(pdv[0]) + eb[col];
    pb[1] = bf2f(pdv[1]) + eb[col + 1];
    pb[2] = bf2f(pdv[2]) + eb[col + 2];
    pb[3] = bf2f(pdv[3]) + eb[col + 3];

    f32x4 accv = (f32x4){0.f, 0.f, 0.f, 0.f};
    const int s0r = row_start[node], s1r = row_start[node + 1];

    if (s1r > s0r) {
        const int jlast = s1r - 1;
        int j1 = (s0r + 1 < jlast) ? s0r + 1 : jlast;
        int sa = src_perm[s0r];
        int sb = src_perm[j1];
        u16x4 psa = *(const u16x4*)(P + (size_t)sa * 768 + col);
        u16x4 psb = *(const u16x4*)(P + (size_t)sb * 768 + col);
        u32 eva = eattr_p32[(size_t)s0r * 16 + l15];
        u32 evb = eattr_p32[(size_t)j1 * 16 + l15];

        for (int j = s0r; j < s1r; ++j) {
            int jc = (j + 2 < jlast) ? j + 2 : jlast;
            int sn = src_perm[jc];
            u16x4 psn = *(const u16x4*)(P + (size_t)sn * 768 + col);
            u32 evn = eattr_p32[(size_t)jc * 16 + l15];

            f32x4 q = pb;
#pragma unroll
            for (int kp = 0; kp < 16; ++kp) {
                u32 evk = (u32)__builtin_amdgcn_readlane((int)eva, kp);
                q[0] = fdot2u(evk, wpk[kp].x, q[0]);
                q[1] = fdot2u(evk, wpk[kp].y, q[1]);
                q[2] = fdot2u(evk, wpk[kp].z, q[2]);
                q[3] = fdot2u(evk, wpk[kp].w, q[3]);
            }
            q[0] += bf2f(psa[0]);
            q[1] += bf2f(psa[1]);
            q[2] += bf2f(psa[2]);
            q[3] += bf2f(psa[3]);
            accv[0] += fmaxf(q[0], 0.f);
            accv[1] += fmaxf(q[1], 0.f);
            accv[2] += fmaxf(q[2], 0.f);
            accv[3] += fmaxf(q[3], 0.f);

            psa = psb; eva = evb;
            psb = psn; evb = evn;
        }
    }

    const float idg = inv_deg[node];
    u16x4 o;
    o[0] = f2bf(accv[0] * idg);
    o[1] = f2bf(accv[1] * idg);
    o[2] = f2bf(accv[2] * idg);
    o[3] = f2bf(accv[3] * idg);
    *(u16x4*)(agg + (size_t)node * 256 + col) = o;
}

// out[node] = dot(h3[node,:], h2w) + h2b  — one wave per node
__global__ __launch_bounds__(256) void head_out(
    const u16* __restrict__ h3,
    const float* __restrict__ h2w,
    const float* __restrict__ h2b,
    float* __restrict__ out)
{
    const int node = (int)((blockIdx.x * 256 + threadIdx.x) >> 6);
    const int lane = threadIdx.x & 63;
    if (node >= NN) return;
    const int col = lane * 4;
    u16x4 hv = *(const u16x4*)(h3 + (size_t)node * 256 + col);
    float4 wv = *(const float4*)(h2w + col);
    float s = bf2f(hv[0]) * wv.x + bf2f(hv[1]) * wv.y +
              bf2f(hv[2]) * wv.z + bf2f(hv[3]) * wv.w;
    for (int off = 32; off > 0; off >>= 1)
        s += __shfl_down(s, off, 64);
    if (lane == 0) out[node] = s + h2b[0];
}

// ---------------- setup kernels ----------------
__global__ void zero_int(int* p, int n) {
    int i = blockIdx.x * 256 + threadIdx.x;
    if (i < n) p[i] = 0;
}

__global__ void hist_k(const int* __restrict__ ei, int* __restrict__ deg) {
    int e = blockIdx.x * 256 + threadIdx.x;
    if (e < NE) atomicAdd(&deg[ei[NE + e]], 1);
}

// phase 1: per-block sums of deg (coalesced)
__global__ __launch_bounds__(256) void block_sum_k(const int* __restrict__ deg,
                                                   int* __restrict__ bsum) {
    __shared__ int sm[4];
    const int i = blockIdx.x * 256 + threadIdx.x;
    int v = (i < NN) ? deg[i] : 0;
    for (int off = 32; off > 0; off >>= 1)
        v += __shfl_down(v, off, 64);
    const int lane = threadIdx.x & 63;
    const int w = threadIdx.x >> 6;
    if (lane == 0) sm[w] = v;
    __syncthreads();
    if (threadIdx.x == 0)
        bsum[blockIdx.x] = sm[0] + sm[1] + sm[2] + sm[3];
}

// phase 2: one small block scans NBLK block sums -> exclusive boff, total
__global__ __launch_bounds__(256) void scan_block_k(const int* __restrict__ bsum,
                                                    int* __restrict__ boff,
                                                    int* __restrict__ row_start) {
    __shared__ int sm[256];
    const int tid = threadIdx.x;
    int v = (tid < NBLK) ? bsum[tid] : 0;
    sm[tid] = v;
    __syncthreads();
    for (int o = 1; o < 256; o <<= 1) {
        int tv = (tid >= o) ? sm[tid - o] : 0;
        __syncthreads();
        sm[tid] += tv;
        __syncthreads();
    }
    if (tid < NBLK) boff[tid] = sm[tid] - v;  // exclusive
    if (tid == NBLK - 1) row_start[NN] = sm[tid];
}

// phase 3: per-block exclusive scan + block offset; coalesced writes
__global__ __launch_bounds__(256) void writeback_k(const int* __restrict__ deg,
                                                   const int* __restrict__ boff,
                                                   int* __restrict__ row_start,
                                                   int* __restrict__ cursor,
                                                   float* __restrict__ inv_deg) {
    __shared__ int sm[256];
    const int tid = threadIdx.x;
    const int i = blockIdx.x * 256 + tid;
    int v = (i < NN) ? deg[i] : 0;
    sm[tid] = v;
    __syncthreads();
    for (int o = 1; o < 256; o <<= 1) {
        int tv = (tid >= o) ? sm[tid - o] : 0;
        __syncthreads();
        sm[tid] += tv;
        __syncthreads();
    }
    if (i < NN) {
        const int rs = boff[blockIdx.x] + sm[tid] - v;
        row_start[i] = rs;
        cursor[i]    = rs;
        inv_deg[i]   = 1.0f / fmaxf((float)v, 1.0f);
    }
}

__global__ void scatter_k(const int* __restrict__ ei, const float* __restrict__ eattr,
                          int* __restrict__ cursor, int* __restrict__ src_perm,
                          u32* __restrict__ eattr_p32) {
    int e = blockIdx.x * 256 + threadIdx.x;
    if (e >= NE) return;
    int s = ei[e], d = ei[NE + e];
    int pos = atomicAdd(&cursor[d], 1);
    src_perm[pos] = s;
    const float* sr = eattr + (size_t)e * 32;
    u32* dr = eattr_p32 + (size_t)pos * 16;
#pragma unroll
    for (int j = 0; j < 16; ++j)
        dr[j] = packh2(sr[2 * j], sr[2 * j + 1]);
}

// jobs: tr=1: dst[n*K+k] = bf16(src[k*256+n])
//       tr=2: We pack: dst32[kp*256+c] = packh2(src[2kp*256+c], src[(2kp+1)*256+c])
struct TJob { const float* src; u16* dst; int K; int ksh; int tr; };
struct TJobs { TJob j[16]; };

__global__ void transpose_k(TJobs jobs) {
    TJob jb = jobs.j[blockIdx.y];
    int idx = blockIdx.x * 256 + threadIdx.x;
    if (idx >= (jb.K << 8)) return;
    if (jb.tr == 1) {
        int n = idx >> jb.ksh;
        int k = idx & (jb.K - 1);
        jb.dst[idx] = f2bf(jb.src[k * 256 + n]);
    } else {
        int kp = idx >> 8;
        int c = idx & 255;
        ((u32*)jb.dst)[idx] = packh2(jb.src[(2 * kp) * 256 + c],
                                     jb.src[(2 * kp + 1) * 256 + c]);
    }
}

__global__ void cvt_f32_bf16(const float* __restrict__ src, u16* __restrict__ dst, int n) {
    int i = blockIdx.x * 256 + threadIdx.x;
    if (i < n) dst[i] = f2bf(src[i]);
}

// ---------------------------------------------------------------------------
extern "C" void kernel_launch(void* const* d_in, const int* in_sizes, int n_in,
                              void* d_out, int out_size, void* d_ws, size_t ws_size,
                              hipStream_t stream) {
    const float* x     = (const float*)d_in[0];
    const int*   ei    = (const int*)d_in[1];
    const float* eattr = (const float*)d_in[2];
    const float* e0_w  = (const float*)d_in[3];
    const float* e0_b  = (const float*)d_in[4];
    const float* n0_w  = (const float*)d_in[5];
    const float* n0_b  = (const float*)d_in[6];
    const float* e_w   = (const float*)d_in[7];
    const float* e_b   = (const float*)d_in[8];
    const float* n_w   = (const float*)d_in[9];
    const float* n_b   = (const float*)d_in[10];
    const float* h1_w  = (const float*)d_in[11];
    const float* h1_b  = (const float*)d_in[12];
    const float* h2_w  = (const float*)d_in[13];
    const float* h2_b  = (const float*)d_in[14];
    float* out = (float*)d_out;
    (void)in_sizes; (void)n_in; (void)out_size; (void)ws_size;

    char* base = (char*)d_ws;
    size_t off = 0;
    auto alloc = [&](size_t nbytes) -> void* {
        void* p = base + off;
        off += (nbytes + 255) & ~(size_t)255;
        return p;
    };

    int*   deg       = (int*)alloc(NN * 4);
    int*   row_start = (int*)alloc((NN + 1) * 4);
    int*   cursor    = (int*)alloc(NN * 4);
    float* invdeg    = (float*)alloc(NN * 4);
    int*   bsum      = (int*)alloc(NBLK * 4);
    int*   boff      = (int*)alloc(NBLK * 4);
    int*   src_perm  = (int*)alloc(NE * 4);
    u32*   eattr_p32 = (u32*)alloc((size_t)NE * 16 * 4);
    u16*   WcatT0    = (u16*)alloc(768 * 128 * 2);
    u16*   WcatT1    = (u16*)alloc(768 * 256 * 2);
    u16*   WcatT2    = (u16*)alloc(768 * 256 * 2);
    u32*   WePk0     = (u32*)alloc(16 * 256 * 4);
    u32*   WePk1     = (u32*)alloc(16 * 256 * 4);
    u32*   WePk2     = (u32*)alloc(16 * 256 * 4);
    u16*   NbT0      = (u16*)alloc(256 * 256 * 2);
    u16*   NbT1      = (u16*)alloc(256 * 256 * 2);
    u16*   NbT2      = (u16*)alloc(256 * 256 * 2);
    u16*   H1T       = (u16*)alloc(256 * 256 * 2);
    u16*   P         = (u16*)alloc((size_t)NN * 768 * 2);
    u16*   aggb      = (u16*)alloc((size_t)NN * 256 * 2);
    u16*   hb        = (u16*)alloc((size_t)NN * 256 * 2);
    u16*   xb        = aggb;  // alias: xb dead before aggb first written

    // ---- CSR build + weight prep ----
    zero_int<<<(NN + 255) / 256, 256, 0, stream>>>(deg, NN);
    hist_k<<<(NE + 255) / 256, 256, 0, stream>>>(ei, deg);
    block_sum_k<<<NBLK, 256, 0, stream>>>(deg, bsum);
    scan_block_k<<<1, 256, 0, stream>>>(bsum, boff, row_start);
    writeback_k<<<NBLK, 256, 0, stream>>>(deg, boff, row_start, cursor, invdeg);
    scatter_k<<<(NE + 255) / 256, 256, 0, stream>>>(ei, eattr, cursor, src_perm, eattr_p32);

    const float* ew2 = e_w + 544 * 256;
    const float* nw2 = n_w + 512 * 256;

    TJobs tj;
    auto setj = [&](int i, const float* s, void* d, int K, int tr) {
        tj.j[i].src = s; tj.j[i].dst = (u16*)d; tj.j[i].K = K; tj.j[i].tr = tr;
        tj.j[i].ksh = (K == 256) ? 8 : (K == 128 ? 7 : 5);
    };
    setj(0,  e0_w,             WcatT0,             128, 1);
    setj(1,  e0_w + 128 * 256, WcatT0 + 256 * 128, 128, 1);
    setj(2,  n0_w,             WcatT0 + 512 * 128, 128, 1);
    setj(3,  n0_w + 128 * 256, NbT0,               256, 1);
    setj(4,  e_w,              WcatT1,             256, 1);
    setj(5,  e_w + 256 * 256,  WcatT1 + 256 * 256, 256, 1);
    setj(6,  n_w,              WcatT1 + 512 * 256, 256, 1);
    setj(7,  n_w + 256 * 256,  NbT1,               256, 1);
    setj(8,  ew2,              WcatT2,             256, 1);
    setj(9,  ew2 + 256 * 256,  WcatT2 + 256 * 256, 256, 1);
    setj(10, nw2,              WcatT2 + 512 * 256, 256, 1);
    setj(11, nw2 + 256 * 256,  NbT2,               256, 1);
    setj(12, h1_w,             H1T,                256, 1);
    setj(13, e0_w + 256 * 256, WePk0,              16,  2);
    setj(14, e_w + 512 * 256,  WePk1,              16,  2);
    setj(15, ew2 + 512 * 256,  WePk2,              16,  2);
    transpose_k<<<dim3(256, 16), 256, 0, stream>>>(tj);

    cvt_f32_bf16<<<(NN * 128 + 255) / 256, 256, 0, stream>>>(x, xb, NN * 128);

    const int MT = (NN + 127) / 128;  // 391
    u16* WcatT[3] = {WcatT0, WcatT1, WcatT2};
    u32* WePk[3]  = {WePk0, WePk1, WePk2};
    u16* NbT[3]   = {NbT0, NbT1, NbT2};
    const float* ebs[3] = {e0_b, e_b, e_b + 256};
    const float* nbs[3] = {n0_b, n_b, n_b + 256};

    for (int l = 0; l < 3; ++l) {
        const u16* hin = (l == 0) ? xb : hb;
        const int kin = (l == 0) ? 128 : 256;
        // P = hin @ [Ws | Wd | ntop]   -> [NN, 768]
        gemm_bt<<<dim3(MT, 6), 256, 0, stream>>>(hin, kin, WcatT[l], P, 768, NN, kin,
                                                 nullptr, nullptr, 0, 0);
        // agg = mean_dst relu(Ps[src] + Pd[dst] + eattr@We + eb)
        edge_agg_fused<<<NN / 4, 256, 0, stream>>>(P, eattr_p32, WePk[l], row_start,
                                                   src_perm, invdeg, ebs[l], aggb);
        // h = relu(agg @ nbot + R + nb)
        gemm_bt<<<dim3(MT, 2), 256, 0, stream>>>(aggb, 256, NbT[l], hb, 256, NN, 256,
                                                 nbs[l], P + 512, 768, 1);
    }
    // head: h3 = relu(h @ h1_w + h1_b); out = h3 @ h2_w + h2_b
    gemm_bt<<<dim3(MT, 2), 256, 0, stream>>>(hb, 256, H1T, aggb, 256, NN, 256,
                                             h1_b, nullptr, 0, 1);
    head_out<<<NN / 4, 256, 0, stream>>>(aggb, h2_w, h2_b, out);
}